// Round 9
// baseline (239.234 us; speedup 1.0000x reference)
//
#include <hip/hip_runtime.h>
#include <hip/hip_bf16.h>

#define N_NODES 50000
#define N_EDGES 800000
#define F 128
#define PAD_ROWS 64   // tail-tile slack for fused_gemm A-loads
#define SCAN_BLK 256
#define SCAN_NB ((N_NODES + SCAN_BLK - 1) / SCAN_BLK)   // 196

typedef _Float16 half8 __attribute__((ext_vector_type(8)));
typedef float floatx4 __attribute__((ext_vector_type(4)));

__device__ inline float wave_sum(float v) {
    #pragma unroll
    for (int o = 32; o > 0; o >>= 1) v += __shfl_xor(v, o);
    return v;
}

__device__ inline float m_of(unsigned u) {
    union { unsigned short s; _Float16 h; } c;
    c.s = (unsigned short)(u >> 16);
    return (float)c.h;
}

// ---------------- k_prep: feat->fp16, weights->fp16, degree+rank, wsum ----------------
// N_EDGES == N_NODES*F/8 == 800000: one grid covers all jobs.
__global__ __launch_bounds__(256) void k_prep(const float* __restrict__ feat,
                                              const float* __restrict__ efeat,
                                              const float* __restrict__ Wp,
                                              const float* __restrict__ Ws,
                                              const int* __restrict__ dst,
                                              _Float16* __restrict__ featH,
                                              _Float16* __restrict__ WpH,
                                              _Float16* __restrict__ WsH,
                                              int* __restrict__ degI,
                                              float* __restrict__ wsumF,
                                              int* __restrict__ rank) {
    int i = blockIdx.x * 256 + threadIdx.x;
    if (i < N_NODES * F / 8) {
        const float4* p = (const float4*)feat + (size_t)i * 2;
        float4 a = p[0], b = p[1];
        half8 h;
        h[0]=(_Float16)a.x; h[1]=(_Float16)a.y; h[2]=(_Float16)a.z; h[3]=(_Float16)a.w;
        h[4]=(_Float16)b.x; h[5]=(_Float16)b.y; h[6]=(_Float16)b.z; h[7]=(_Float16)b.w;
        ((half8*)featH)[i] = h;
    }
    if (i < N_EDGES) {
        int d = dst[i];
        rank[i] = atomicAdd(&degI[d], 1);
        atomicAdd(&wsumF[d], efeat[i]);
    }
    if (i < F * F / 8) {
        const float4* pp = (const float4*)Wp + (size_t)i * 2;
        const float4* ps = (const float4*)Ws + (size_t)i * 2;
        float4 a = pp[0], b = pp[1];
        half8 h;
        h[0]=(_Float16)a.x; h[1]=(_Float16)a.y; h[2]=(_Float16)a.z; h[3]=(_Float16)a.w;
        h[4]=(_Float16)b.x; h[5]=(_Float16)b.y; h[6]=(_Float16)b.z; h[7]=(_Float16)b.w;
        ((half8*)WpH)[i] = h;
        a = ps[0]; b = ps[1];
        h[0]=(_Float16)a.x; h[1]=(_Float16)a.y; h[2]=(_Float16)a.z; h[3]=(_Float16)a.w;
        h[4]=(_Float16)b.x; h[5]=(_Float16)b.y; h[6]=(_Float16)b.z; h[7]=(_Float16)b.w;
        ((half8*)WsH)[i] = h;
    }
}

// ---------------- parallel 3-phase exclusive scan ----------------
__global__ __launch_bounds__(SCAN_BLK) void k_scan1(const int* __restrict__ degI,
                                                    int* __restrict__ blockSums) {
    __shared__ int s[SCAN_BLK];
    int t = threadIdx.x;
    int i = blockIdx.x * SCAN_BLK + t;
    s[t] = (i < N_NODES) ? degI[i] : 0;
    __syncthreads();
    for (int o = SCAN_BLK / 2; o > 0; o >>= 1) {
        if (t < o) s[t] += s[t + o];
        __syncthreads();
    }
    if (t == 0) blockSums[blockIdx.x] = s[0];
}

__global__ __launch_bounds__(SCAN_BLK) void k_scan2(int* __restrict__ blockSums,
                                                    int* __restrict__ offsets) {
    __shared__ int s[SCAN_BLK];
    int t = threadIdx.x;
    int v = (t < SCAN_NB) ? blockSums[t] : 0;
    s[t] = v;
    __syncthreads();
    for (int o = 1; o < SCAN_BLK; o <<= 1) {
        int u = (t >= o) ? s[t - o] : 0;
        __syncthreads();
        s[t] += u;
        __syncthreads();
    }
    if (t < SCAN_NB) blockSums[t] = s[t] - v;   // exclusive prefix, in place
    if (t == 0) offsets[N_NODES] = N_EDGES;
}

__global__ __launch_bounds__(SCAN_BLK) void k_scan3(const int* __restrict__ degI,
                                                    const int* __restrict__ blockSums,
                                                    int* __restrict__ offsets) {
    __shared__ int s[SCAN_BLK];
    int t = threadIdx.x;
    int i = blockIdx.x * SCAN_BLK + t;
    int v = (i < N_NODES) ? degI[i] : 0;
    s[t] = v;
    __syncthreads();
    for (int o = 1; o < SCAN_BLK; o <<= 1) {
        int u = (t >= o) ? s[t - o] : 0;
        __syncthreads();
        s[t] += u;
        __syncthreads();
    }
    if (i < N_NODES) offsets[i] = s[t] - v + blockSums[blockIdx.x];
}

// ---------------- k_fill: m=exp(-w/wsum); CSR scatter of packed (src:u16, m:fp16) ----------------
__global__ __launch_bounds__(256) void k_fill(const int* __restrict__ src,
                                              const int* __restrict__ dst,
                                              const float* __restrict__ efeat,
                                              const float* __restrict__ wsumF,
                                              const int* __restrict__ offsets,
                                              const int* __restrict__ rank,
                                              unsigned* __restrict__ csr) {
    int e = blockIdx.x * 256 + threadIdx.x;
    if (e < N_EDGES) {
        int d = dst[e];
        float m = __expf(-efeat[e] / wsumF[d]);
        union { _Float16 h; unsigned short s; } c;
        c.h = (_Float16)m;
        int pos = offsets[d] + rank[e];
        csr[pos] = (unsigned)src[e] | ((unsigned)c.s << 16);
    }
}

// ---------------- k_gather: one wave per node, 8 feat rows in flight ----------------
__global__ __launch_bounds__(256) void k_gather(const int* __restrict__ offsets,
                                                const unsigned* __restrict__ csr,
                                                const _Float16* __restrict__ featH,
                                                float* __restrict__ msum,
                                                _Float16* __restrict__ aggH) {
    int wid  = (blockIdx.x * 256 + threadIdx.x) >> 6;   // node id
    int lane = threadIdx.x & 63;
    if (wid >= N_NODES) return;
    int beg = offsets[wid], end = offsets[wid + 1];
    int grp = lane >> 4;        // 0..3
    int lig = lane & 15;        // lane in group

    float acc[8];
    #pragma unroll
    for (int k = 0; k < 8; ++k) acc[k] = 0.f;
    float msacc = 0.f;

    for (int c = beg; c < end; c += 64) {
        int j = c + lane;
        int cnt = end - c; if (cnt > 64) cnt = 64;
        unsigned u = (j < end) ? csr[j] : 0u;
        msacc += m_of(u);                      // m_of(0) == 0
        for (int it = 0; it < cnt; it += 8) {
            int idx1 = it + grp;
            int idx2 = it + 4 + grp;
            unsigned u1 = __shfl(u, idx1);
            unsigned u2 = __shfl(u, idx2);
            bool p1 = idx1 < cnt, p2 = idx2 < cnt;
            half8 v1, v2;
            float m1 = 0.f, m2 = 0.f;
            if (p1) {
                v1 = *(const half8*)(featH + (size_t)(u1 & 0xFFFFu) * F + lig * 8);
                m1 = m_of(u1);
            }
            if (p2) {
                v2 = *(const half8*)(featH + (size_t)(u2 & 0xFFFFu) * F + lig * 8);
                m2 = m_of(u2);
            }
            if (p1) {
                #pragma unroll
                for (int k = 0; k < 8; ++k) acc[k] += m1 * (float)v1[k];
            }
            if (p2) {
                #pragma unroll
                for (int k = 0; k < 8; ++k) acc[k] += m2 * (float)v2[k];
            }
        }
    }

    #pragma unroll
    for (int k = 0; k < 8; ++k) {
        acc[k] += __shfl_xor(acc[k], 16);
        acc[k] += __shfl_xor(acc[k], 32);
    }
    msacc = wave_sum(msacc);

    if (grp == 0) {
        half8 o;
        #pragma unroll
        for (int k = 0; k < 8; ++k) o[k] = (_Float16)acc[k];
        ((half8*)(aggH + (size_t)wid * F))[lig] = o;
    }
    if (lane == 0) msum[wid] = msacc;
}

// ---------------- fused_gemm: dual MFMA GEMM, weights staged in LDS ----------------
// 512 threads = 8 waves, 16 nodes/wave -> 128 nodes/block. B-fragment-ordered LDS.
__global__ __launch_bounds__(512, 4) void fused_gemm(const _Float16* __restrict__ featH,
                                                     const _Float16* __restrict__ aggH,
                                                     const _Float16* __restrict__ WpH,
                                                     const float* __restrict__ bp,
                                                     const _Float16* __restrict__ WsH,
                                                     const float* __restrict__ bs,
                                                     const float* __restrict__ msum,
                                                     const int* __restrict__ offsets,
                                                     float* __restrict__ out) {
    __shared__ half8 sBS[2048];   // 32 KB
    __shared__ half8 sBP[2048];   // 32 KB

    int t = threadIdx.x;
    for (int c = t; c < 2048; c += 512) {
        int o  = c >> 4;
        int k8 = c & 15;
        int lane = (o & 15) | ((k8 & 3) << 4);
        int slot = ((o >> 4) * 4 + (k8 >> 2)) * 64 + lane;
        sBS[slot] = ((const half8*)WsH)[c];
        sBP[slot] = ((const half8*)WpH)[c];
    }
    __syncthreads();

    int wv   = t >> 6;
    int lane = t & 63;
    int n0   = blockIdx.x * 128 + wv * 16;   // tail waves compute garbage on pad rows; stores guarded
    int lrow = lane & 15;
    int quad = lane >> 4;

    floatx4 accS[8], accP[8];
    #pragma unroll
    for (int c = 0; c < 8; ++c) {
        accS[c] = (floatx4){0.f, 0.f, 0.f, 0.f};
        accP[c] = (floatx4){0.f, 0.f, 0.f, 0.f};
    }

    const half8* fr = (const half8*)(featH + (size_t)(n0 + lrow) * F) + quad;
    const half8* ar = (const half8*)(aggH  + (size_t)(n0 + lrow) * F) + quad;

    #pragma unroll
    for (int kt = 0; kt < 4; ++kt) {
        half8 aF = fr[kt * 4];
        half8 aA = ar[kt * 4];
        #pragma unroll
        for (int ct = 0; ct < 8; ++ct) {
            half8 bS = sBS[(ct * 4 + kt) * 64 + lane];
            half8 bP = sBP[(ct * 4 + kt) * 64 + lane];
            accS[ct] = __builtin_amdgcn_mfma_f32_16x16x32_f16(aF, bS, accS[ct], 0, 0, 0);
            accP[ct] = __builtin_amdgcn_mfma_f32_16x16x32_f16(aA, bP, accP[ct], 0, 0, 0);
        }
    }

    float ms[4], inv[4];
    int gn[4];
    #pragma unroll
    for (int r = 0; r < 4; ++r) {
        int g = n0 + quad * 4 + r;
        gn[r] = g;
        bool ok = g < N_NODES;
        ms[r]  = ok ? msum[g] : 0.f;
        float dv = ok ? fmaxf((float)(offsets[g + 1] - offsets[g]), 1.0f) : 1.0f;
        inv[r] = 1.0f / dv;
    }
    #pragma unroll
    for (int ct = 0; ct < 8; ++ct) {
        int c = ct * 16 + lrow;
        float bsv = bs[c], bpv = bp[c];
        #pragma unroll
        for (int r = 0; r < 4; ++r) {
            if (gn[r] < N_NODES)
                out[(size_t)gn[r] * F + c] = accS[ct][r] + bsv + (accP[ct][r] + ms[r] * bpv) * inv[r];
        }
    }
}

static inline char* align16(char* p) {
    return (char*)(((uintptr_t)p + 15) & ~(uintptr_t)15);
}

extern "C" void kernel_launch(void* const* d_in, const int* in_sizes, int n_in,
                              void* d_out, int out_size, void* d_ws, size_t ws_size,
                              hipStream_t stream) {
    const float* feat  = (const float*)d_in[0];
    const float* efeat = (const float*)d_in[1];
    const int*   src   = (const int*)d_in[2];
    const int*   dst   = (const int*)d_in[3];
    const float* Wp    = (const float*)d_in[4];
    const float* bp    = (const float*)d_in[5];
    const float* Ws    = (const float*)d_in[6];
    const float* bs    = (const float*)d_in[7];
    float* out = (float*)d_out;

    // workspace layout
    char* p = (char*)d_ws;
    int*      degI     = (int*)p;      p += (size_t)N_NODES * 4;            // 200000B, 16-aligned
    float*    wsumF    = (float*)p;    p += (size_t)N_NODES * 4;            p = align16(p);
    int*      offsets  = (int*)p;      p += (size_t)(N_NODES + 1) * 4;      p = align16(p);
    int*      blockSums= (int*)p;      p += (size_t)SCAN_BLK * 4;           p = align16(p);
    unsigned* csr      = (unsigned*)p; p += (size_t)N_EDGES * 4;            p = align16(p);
    float*    msum     = (float*)p;    p += (size_t)N_NODES * 4;            p = align16(p);
    _Float16* featH    = (_Float16*)p; p += (size_t)(N_NODES + PAD_ROWS) * F * 2; p = align16(p);
    _Float16* aggH     = (_Float16*)p; p += (size_t)(N_NODES + PAD_ROWS) * F * 2; p = align16(p);
    _Float16* WsH      = (_Float16*)p; p += (size_t)F * F * 2;              p = align16(p);
    _Float16* WpH      = (_Float16*)p;
    // rank lives in aggH's region: written by k_prep, read by k_fill,
    // both strictly before k_gather writes aggH. 3.2 MB <= 12.8 MB.
    int* rank = (int*)aggH;

    // zero degI + wsumF (contiguous 400 KB at base)
    hipMemsetAsync(d_ws, 0, (size_t)2 * N_NODES * 4, stream);

    k_prep<<<(N_EDGES + 255) / 256, 256, 0, stream>>>(feat, efeat, Wp, Ws, dst,
                                                      featH, WpH, WsH, degI, wsumF, rank);
    k_scan1<<<SCAN_NB, SCAN_BLK, 0, stream>>>(degI, blockSums);
    k_scan2<<<1, SCAN_BLK, 0, stream>>>(blockSums, offsets);
    k_scan3<<<SCAN_NB, SCAN_BLK, 0, stream>>>(degI, blockSums, offsets);
    k_fill<<<(N_EDGES + 255) / 256, 256, 0, stream>>>(src, dst, efeat, wsumF, offsets, rank, csr);
    k_gather<<<(N_NODES * 64 + 255) / 256, 256, 0, stream>>>(offsets, csr, featH, msum, aggH);
    fused_gemm<<<(N_NODES + 127) / 128, 512, 0, stream>>>(featH, aggH, WpH, bp, WsH, bs, msum, offsets, out);
}

// Round 10
// 211.050 us; speedup vs baseline: 1.1335x; 1.1335x over previous
//
#include <hip/hip_runtime.h>
#include <hip/hip_bf16.h>

#define N_NODES 50000
#define N_EDGES 800000
#define F 128
#define PAD_ROWS 64   // tail-tile slack for fused_gemm A-loads
#define SCAN_BLK 256
#define SCAN_NB ((N_NODES + SCAN_BLK - 1) / SCAN_BLK)   // 196

typedef _Float16 half8 __attribute__((ext_vector_type(8)));
typedef float floatx4 __attribute__((ext_vector_type(4)));

__device__ inline float wave_sum(float v) {
    #pragma unroll
    for (int o = 32; o > 0; o >>= 1) v += __shfl_xor(v, o);
    return v;
}

// high 16 bits hold an fp16 payload
__device__ inline float hi16_of(unsigned u) {
    union { unsigned short s; _Float16 h; } c;
    c.s = (unsigned short)(u >> 16);
    return (float)c.h;
}

// ---------------- k_prep: feat->fp16, weights->fp16, degree histogram + rank ----------------
// N_EDGES == N_NODES*F/8 == 800000: one grid covers all jobs. NO contended float atomics.
__global__ __launch_bounds__(256) void k_prep(const float* __restrict__ feat,
                                              const float* __restrict__ Wp,
                                              const float* __restrict__ Ws,
                                              const int* __restrict__ dst,
                                              _Float16* __restrict__ featH,
                                              _Float16* __restrict__ WpH,
                                              _Float16* __restrict__ WsH,
                                              int* __restrict__ degI,
                                              int* __restrict__ rank) {
    int i = blockIdx.x * 256 + threadIdx.x;
    if (i < N_NODES * F / 8) {
        const float4* p = (const float4*)feat + (size_t)i * 2;
        float4 a = p[0], b = p[1];
        half8 h;
        h[0]=(_Float16)a.x; h[1]=(_Float16)a.y; h[2]=(_Float16)a.z; h[3]=(_Float16)a.w;
        h[4]=(_Float16)b.x; h[5]=(_Float16)b.y; h[6]=(_Float16)b.z; h[7]=(_Float16)b.w;
        ((half8*)featH)[i] = h;
    }
    if (i < N_EDGES) {
        rank[i] = atomicAdd(&degI[dst[i]], 1);
    }
    if (i < F * F / 8) {
        const float4* pp = (const float4*)Wp + (size_t)i * 2;
        const float4* ps = (const float4*)Ws + (size_t)i * 2;
        float4 a = pp[0], b = pp[1];
        half8 h;
        h[0]=(_Float16)a.x; h[1]=(_Float16)a.y; h[2]=(_Float16)a.z; h[3]=(_Float16)a.w;
        h[4]=(_Float16)b.x; h[5]=(_Float16)b.y; h[6]=(_Float16)b.z; h[7]=(_Float16)b.w;
        ((half8*)WpH)[i] = h;
        a = ps[0]; b = ps[1];
        h[0]=(_Float16)a.x; h[1]=(_Float16)a.y; h[2]=(_Float16)a.z; h[3]=(_Float16)a.w;
        h[4]=(_Float16)b.x; h[5]=(_Float16)b.y; h[6]=(_Float16)b.z; h[7]=(_Float16)b.w;
        ((half8*)WsH)[i] = h;
    }
}

// ---------------- parallel 3-phase exclusive scan ----------------
__global__ __launch_bounds__(SCAN_BLK) void k_scan1(const int* __restrict__ degI,
                                                    int* __restrict__ blockSums) {
    __shared__ int s[SCAN_BLK];
    int t = threadIdx.x;
    int i = blockIdx.x * SCAN_BLK + t;
    s[t] = (i < N_NODES) ? degI[i] : 0;
    __syncthreads();
    for (int o = SCAN_BLK / 2; o > 0; o >>= 1) {
        if (t < o) s[t] += s[t + o];
        __syncthreads();
    }
    if (t == 0) blockSums[blockIdx.x] = s[0];
}

__global__ __launch_bounds__(SCAN_BLK) void k_scan2(int* __restrict__ blockSums,
                                                    int* __restrict__ offsets) {
    __shared__ int s[SCAN_BLK];
    int t = threadIdx.x;
    int v = (t < SCAN_NB) ? blockSums[t] : 0;
    s[t] = v;
    __syncthreads();
    for (int o = 1; o < SCAN_BLK; o <<= 1) {
        int u = (t >= o) ? s[t - o] : 0;
        __syncthreads();
        s[t] += u;
        __syncthreads();
    }
    if (t < SCAN_NB) blockSums[t] = s[t] - v;   // exclusive prefix, in place
    if (t == 0) offsets[N_NODES] = N_EDGES;
}

__global__ __launch_bounds__(SCAN_BLK) void k_scan3(const int* __restrict__ degI,
                                                    const int* __restrict__ blockSums,
                                                    int* __restrict__ offsets) {
    __shared__ int s[SCAN_BLK];
    int t = threadIdx.x;
    int i = blockIdx.x * SCAN_BLK + t;
    int v = (i < N_NODES) ? degI[i] : 0;
    s[t] = v;
    __syncthreads();
    for (int o = 1; o < SCAN_BLK; o <<= 1) {
        int u = (t >= o) ? s[t - o] : 0;
        __syncthreads();
        s[t] += u;
        __syncthreads();
    }
    if (i < N_NODES) offsets[i] = s[t] - v + blockSums[blockIdx.x];
}

// ---------------- k_fill: CSR scatter of packed (src:u16, w:fp16), no atomics, no exp ----------------
__global__ __launch_bounds__(256) void k_fill(const int* __restrict__ src,
                                              const int* __restrict__ dst,
                                              const float* __restrict__ efeat,
                                              const int* __restrict__ offsets,
                                              const int* __restrict__ rank,
                                              unsigned* __restrict__ csr) {
    int e = blockIdx.x * 256 + threadIdx.x;
    if (e < N_EDGES) {
        union { _Float16 h; unsigned short s; } c;
        c.h = (_Float16)efeat[e];
        int pos = offsets[dst[e]] + rank[e];
        csr[pos] = (unsigned)src[e] | ((unsigned)c.s << 16);
    }
}

// ---------------- k_wsum: one wave per node, segment-sum w -> invw ----------------
__global__ __launch_bounds__(256) void k_wsum(const int* __restrict__ offsets,
                                              const unsigned* __restrict__ csr,
                                              float* __restrict__ invw) {
    int wid  = (blockIdx.x * 256 + threadIdx.x) >> 6;
    int lane = threadIdx.x & 63;
    if (wid >= N_NODES) return;
    int beg = offsets[wid], end = offsets[wid + 1];
    float s = 0.f;
    for (int j = beg + lane; j < end; j += 64) s += hi16_of(csr[j]);
    s = wave_sum(s);
    if (lane == 0) invw[wid] = (end > beg) ? (1.0f / s) : 0.0f;
}

// ---------------- k_gather: one wave per node, 8 feat rows in flight ----------------
// m = exp(-w * invw[node]) recomputed after the single shuffle (cheaper than 2nd shuffle).
__global__ __launch_bounds__(256) void k_gather(const int* __restrict__ offsets,
                                                const unsigned* __restrict__ csr,
                                                const float* __restrict__ invw,
                                                const _Float16* __restrict__ featH,
                                                float* __restrict__ msum,
                                                _Float16* __restrict__ aggH) {
    int wid  = (blockIdx.x * 256 + threadIdx.x) >> 6;   // node id
    int lane = threadIdx.x & 63;
    if (wid >= N_NODES) return;
    int beg = offsets[wid], end = offsets[wid + 1];
    float inv = invw[wid];
    int grp = lane >> 4;        // 0..3
    int lig = lane & 15;        // lane in group

    float acc[8];
    #pragma unroll
    for (int k = 0; k < 8; ++k) acc[k] = 0.f;
    float msacc = 0.f;

    for (int c = beg; c < end; c += 64) {
        int j = c + lane;
        int cnt = end - c; if (cnt > 64) cnt = 64;
        unsigned u = (j < end) ? csr[j] : 0u;
        msacc += (j < end) ? __expf(-hi16_of(u) * inv) : 0.f;
        for (int it = 0; it < cnt; it += 8) {
            int idx1 = it + grp;
            int idx2 = it + 4 + grp;
            unsigned u1 = __shfl(u, idx1);
            unsigned u2 = __shfl(u, idx2);
            bool p1 = idx1 < cnt, p2 = idx2 < cnt;
            half8 v1, v2;
            float m1 = 0.f, m2 = 0.f;
            if (p1) {
                v1 = *(const half8*)(featH + (size_t)(u1 & 0xFFFFu) * F + lig * 8);
                m1 = __expf(-hi16_of(u1) * inv);
            }
            if (p2) {
                v2 = *(const half8*)(featH + (size_t)(u2 & 0xFFFFu) * F + lig * 8);
                m2 = __expf(-hi16_of(u2) * inv);
            }
            if (p1) {
                #pragma unroll
                for (int k = 0; k < 8; ++k) acc[k] += m1 * (float)v1[k];
            }
            if (p2) {
                #pragma unroll
                for (int k = 0; k < 8; ++k) acc[k] += m2 * (float)v2[k];
            }
        }
    }

    #pragma unroll
    for (int k = 0; k < 8; ++k) {
        acc[k] += __shfl_xor(acc[k], 16);
        acc[k] += __shfl_xor(acc[k], 32);
    }
    msacc = wave_sum(msacc);

    if (grp == 0) {
        half8 o;
        #pragma unroll
        for (int k = 0; k < 8; ++k) o[k] = (_Float16)acc[k];
        ((half8*)(aggH + (size_t)wid * F))[lig] = o;
    }
    if (lane == 0) msum[wid] = msacc;
}

// ---------------- fused_gemm: dual MFMA GEMM, weights staged in LDS ----------------
// 512 threads = 8 waves, 16 nodes/wave -> 128 nodes/block. B-fragment-ordered LDS.
__global__ __launch_bounds__(512, 4) void fused_gemm(const _Float16* __restrict__ featH,
                                                     const _Float16* __restrict__ aggH,
                                                     const _Float16* __restrict__ WpH,
                                                     const float* __restrict__ bp,
                                                     const _Float16* __restrict__ WsH,
                                                     const float* __restrict__ bs,
                                                     const float* __restrict__ msum,
                                                     const int* __restrict__ offsets,
                                                     float* __restrict__ out) {
    __shared__ half8 sBS[2048];   // 32 KB
    __shared__ half8 sBP[2048];   // 32 KB

    int t = threadIdx.x;
    for (int c = t; c < 2048; c += 512) {
        int o  = c >> 4;
        int k8 = c & 15;
        int lane = (o & 15) | ((k8 & 3) << 4);
        int slot = ((o >> 4) * 4 + (k8 >> 2)) * 64 + lane;
        sBS[slot] = ((const half8*)WsH)[c];
        sBP[slot] = ((const half8*)WpH)[c];
    }
    __syncthreads();

    int wv   = t >> 6;
    int lane = t & 63;
    int n0   = blockIdx.x * 128 + wv * 16;   // tail waves compute garbage on pad rows; stores guarded
    int lrow = lane & 15;
    int quad = lane >> 4;

    floatx4 accS[8], accP[8];
    #pragma unroll
    for (int c = 0; c < 8; ++c) {
        accS[c] = (floatx4){0.f, 0.f, 0.f, 0.f};
        accP[c] = (floatx4){0.f, 0.f, 0.f, 0.f};
    }

    const half8* fr = (const half8*)(featH + (size_t)(n0 + lrow) * F) + quad;
    const half8* ar = (const half8*)(aggH  + (size_t)(n0 + lrow) * F) + quad;

    #pragma unroll
    for (int kt = 0; kt < 4; ++kt) {
        half8 aF = fr[kt * 4];
        half8 aA = ar[kt * 4];
        #pragma unroll
        for (int ct = 0; ct < 8; ++ct) {
            half8 bS = sBS[(ct * 4 + kt) * 64 + lane];
            half8 bP = sBP[(ct * 4 + kt) * 64 + lane];
            accS[ct] = __builtin_amdgcn_mfma_f32_16x16x32_f16(aF, bS, accS[ct], 0, 0, 0);
            accP[ct] = __builtin_amdgcn_mfma_f32_16x16x32_f16(aA, bP, accP[ct], 0, 0, 0);
        }
    }

    float ms[4], inv[4];
    int gn[4];
    #pragma unroll
    for (int r = 0; r < 4; ++r) {
        int g = n0 + quad * 4 + r;
        gn[r] = g;
        bool ok = g < N_NODES;
        ms[r]  = ok ? msum[g] : 0.f;
        float dv = ok ? fmaxf((float)(offsets[g + 1] - offsets[g]), 1.0f) : 1.0f;
        inv[r] = 1.0f / dv;
    }
    #pragma unroll
    for (int ct = 0; ct < 8; ++ct) {
        int c = ct * 16 + lrow;
        float bsv = bs[c], bpv = bp[c];
        #pragma unroll
        for (int r = 0; r < 4; ++r) {
            if (gn[r] < N_NODES)
                out[(size_t)gn[r] * F + c] = accS[ct][r] + bsv + (accP[ct][r] + ms[r] * bpv) * inv[r];
        }
    }
}

static inline char* align16(char* p) {
    return (char*)(((uintptr_t)p + 15) & ~(uintptr_t)15);
}

extern "C" void kernel_launch(void* const* d_in, const int* in_sizes, int n_in,
                              void* d_out, int out_size, void* d_ws, size_t ws_size,
                              hipStream_t stream) {
    const float* feat  = (const float*)d_in[0];
    const float* efeat = (const float*)d_in[1];
    const int*   src   = (const int*)d_in[2];
    const int*   dst   = (const int*)d_in[3];
    const float* Wp    = (const float*)d_in[4];
    const float* bp    = (const float*)d_in[5];
    const float* Ws    = (const float*)d_in[6];
    const float* bs    = (const float*)d_in[7];
    float* out = (float*)d_out;

    // workspace layout
    char* p = (char*)d_ws;
    int*      degI     = (int*)p;      p += (size_t)N_NODES * 4;            // 200000B
    float*    invw     = (float*)p;    p += (size_t)N_NODES * 4;            p = align16(p);
    int*      offsets  = (int*)p;      p += (size_t)(N_NODES + 1) * 4;      p = align16(p);
    int*      blockSums= (int*)p;      p += (size_t)SCAN_BLK * 4;           p = align16(p);
    unsigned* csr      = (unsigned*)p; p += (size_t)N_EDGES * 4;            p = align16(p);
    float*    msum     = (float*)p;    p += (size_t)N_NODES * 4;            p = align16(p);
    _Float16* featH    = (_Float16*)p; p += (size_t)(N_NODES + PAD_ROWS) * F * 2; p = align16(p);
    _Float16* aggH     = (_Float16*)p; p += (size_t)(N_NODES + PAD_ROWS) * F * 2; p = align16(p);
    _Float16* WsH      = (_Float16*)p; p += (size_t)F * F * 2;              p = align16(p);
    _Float16* WpH      = (_Float16*)p;
    // rank lives in aggH's region: written by k_prep, read by k_fill,
    // both strictly before k_gather writes aggH. 3.2 MB <= 12.8 MB.
    int* rank = (int*)aggH;

    // zero degI only
    hipMemsetAsync(d_ws, 0, (size_t)N_NODES * 4, stream);

    k_prep<<<(N_EDGES + 255) / 256, 256, 0, stream>>>(feat, Wp, Ws, dst, featH, WpH, WsH, degI, rank);
    k_scan1<<<SCAN_NB, SCAN_BLK, 0, stream>>>(degI, blockSums);
    k_scan2<<<1, SCAN_BLK, 0, stream>>>(blockSums, offsets);
    k_scan3<<<SCAN_NB, SCAN_BLK, 0, stream>>>(degI, blockSums, offsets);
    k_fill<<<(N_EDGES + 255) / 256, 256, 0, stream>>>(src, dst, efeat, offsets, rank, csr);
    k_wsum<<<(N_NODES * 64 + 255) / 256, 256, 0, stream>>>(offsets, csr, invw);
    k_gather<<<(N_NODES * 64 + 255) / 256, 256, 0, stream>>>(offsets, csr, invw, featH, msum, aggH);
    fused_gemm<<<(N_NODES + 127) / 128, 512, 0, stream>>>(featH, aggH, WpH, bp, WsH, bs, msum, offsets, out);
}

// Round 11
// 198.405 us; speedup vs baseline: 1.2058x; 1.0637x over previous
//
#include <hip/hip_runtime.h>
#include <hip/hip_bf16.h>

#define N_NODES 50000
#define N_EDGES 800000
#define F 128
#define PAD_ROWS 64   // tail-tile slack for fused_gemm A-loads
#define SCAN_BLK 256
#define SCAN_NB ((N_NODES + SCAN_BLK - 1) / SCAN_BLK)   // 196
#define NREP 8        // histogram replicas (contention /8)

typedef _Float16 half8 __attribute__((ext_vector_type(8)));
typedef float floatx4 __attribute__((ext_vector_type(4)));

__device__ inline float wave_sum(float v) {
    #pragma unroll
    for (int o = 32; o > 0; o >>= 1) v += __shfl_xor(v, o);
    return v;
}

// high 16 bits hold an fp16 payload
__device__ inline float hi16_of(unsigned u) {
    union { unsigned short s; _Float16 h; } c;
    c.s = (unsigned short)(u >> 16);
    return (float)c.h;
}

// ---------------- k_prep: feat->fp16, weights->fp16, replicated degree histogram + rank ----------------
__global__ __launch_bounds__(256) void k_prep(const float* __restrict__ feat,
                                              const float* __restrict__ Wp,
                                              const float* __restrict__ Ws,
                                              const int* __restrict__ dst,
                                              _Float16* __restrict__ featH,
                                              _Float16* __restrict__ WpH,
                                              _Float16* __restrict__ WsH,
                                              int* __restrict__ degR,
                                              int* __restrict__ rank) {
    int i = blockIdx.x * 256 + threadIdx.x;
    if (i < N_NODES * F / 8) {
        const float4* p = (const float4*)feat + (size_t)i * 2;
        float4 a = p[0], b = p[1];
        half8 h;
        h[0]=(_Float16)a.x; h[1]=(_Float16)a.y; h[2]=(_Float16)a.z; h[3]=(_Float16)a.w;
        h[4]=(_Float16)b.x; h[5]=(_Float16)b.y; h[6]=(_Float16)b.z; h[7]=(_Float16)b.w;
        ((half8*)featH)[i] = h;
    }
    if (i < N_EDGES) {
        int r = i & (NREP - 1);
        rank[i] = atomicAdd(&degR[r * N_NODES + dst[i]], 1);
    }
    if (i < F * F / 8) {
        const float4* pp = (const float4*)Wp + (size_t)i * 2;
        const float4* ps = (const float4*)Ws + (size_t)i * 2;
        float4 a = pp[0], b = pp[1];
        half8 h;
        h[0]=(_Float16)a.x; h[1]=(_Float16)a.y; h[2]=(_Float16)a.z; h[3]=(_Float16)a.w;
        h[4]=(_Float16)b.x; h[5]=(_Float16)b.y; h[6]=(_Float16)b.z; h[7]=(_Float16)b.w;
        ((half8*)WpH)[i] = h;
        a = ps[0]; b = ps[1];
        h[0]=(_Float16)a.x; h[1]=(_Float16)a.y; h[2]=(_Float16)a.z; h[3]=(_Float16)a.w;
        h[4]=(_Float16)b.x; h[5]=(_Float16)b.y; h[6]=(_Float16)b.z; h[7]=(_Float16)b.w;
        ((half8*)WsH)[i] = h;
    }
}

// ---------------- k_scan1: per-node replica prefix + degree + per-block sums ----------------
__global__ __launch_bounds__(SCAN_BLK) void k_scan1(const int* __restrict__ degR,
                                                    int* __restrict__ deg,
                                                    int* __restrict__ repBase,
                                                    int* __restrict__ blockSums) {
    __shared__ int s[SCAN_BLK];
    int t = threadIdx.x;
    int n = blockIdx.x * SCAN_BLK + t;
    int d = 0;
    if (n < N_NODES) {
        #pragma unroll
        for (int r = 0; r < NREP; ++r) {
            repBase[r * N_NODES + n] = d;       // exclusive replica prefix
            d += degR[r * N_NODES + n];         // coalesced plane reads
        }
        deg[n] = d;
    }
    s[t] = (n < N_NODES) ? d : 0;
    __syncthreads();
    for (int o = SCAN_BLK / 2; o > 0; o >>= 1) {
        if (t < o) s[t] += s[t + o];
        __syncthreads();
    }
    if (t == 0) blockSums[blockIdx.x] = s[0];
}

// ---------------- k_scan3: fused top-level + per-block exclusive scan ----------------
// Every block redundantly scans the 196 blockSums in LDS (cheap), takes its prefix.
__global__ __launch_bounds__(SCAN_BLK) void k_scan3(const int* __restrict__ deg,
                                                    const int* __restrict__ blockSums,
                                                    int* __restrict__ offsets) {
    __shared__ int bs[SCAN_BLK];
    __shared__ int s[SCAN_BLK];
    int t = threadIdx.x;
    bs[t] = (t < SCAN_NB) ? blockSums[t] : 0;
    __syncthreads();
    for (int o = 1; o < SCAN_BLK; o <<= 1) {
        int u = (t >= o) ? bs[t - o] : 0;
        __syncthreads();
        bs[t] += u;
        __syncthreads();
    }
    int blockPrefix = (blockIdx.x == 0) ? 0 : bs[blockIdx.x - 1];
    int i = blockIdx.x * SCAN_BLK + t;
    int v = (i < N_NODES) ? deg[i] : 0;
    s[t] = v;
    __syncthreads();
    for (int o = 1; o < SCAN_BLK; o <<= 1) {
        int u = (t >= o) ? s[t - o] : 0;
        __syncthreads();
        s[t] += u;
        __syncthreads();
    }
    if (i < N_NODES) offsets[i] = s[t] - v + blockPrefix;
    if (blockIdx.x == 0 && t == 0) offsets[N_NODES] = N_EDGES;
}

// ---------------- k_fill: CSR scatter of packed (src:u16, w:fp16), no atomics ----------------
__global__ __launch_bounds__(256) void k_fill(const int* __restrict__ src,
                                              const int* __restrict__ dst,
                                              const float* __restrict__ efeat,
                                              const int* __restrict__ offsets,
                                              const int* __restrict__ repBase,
                                              const int* __restrict__ rank,
                                              unsigned* __restrict__ csr) {
    int e = blockIdx.x * 256 + threadIdx.x;
    if (e < N_EDGES) {
        int d = dst[e];
        int r = e & (NREP - 1);
        union { _Float16 h; unsigned short s; } c;
        c.h = (_Float16)efeat[e];
        int pos = offsets[d] + repBase[r * N_NODES + d] + rank[e];
        csr[pos] = (unsigned)src[e] | ((unsigned)c.s << 16);
    }
}

// ---------------- k_gather: one wave per node; wsum sweep + 8 feat rows in flight ----------------
__global__ __launch_bounds__(256) void k_gather(const int* __restrict__ offsets,
                                                const unsigned* __restrict__ csr,
                                                const _Float16* __restrict__ featH,
                                                float* __restrict__ msum,
                                                _Float16* __restrict__ aggH) {
    int wid  = (blockIdx.x * 256 + threadIdx.x) >> 6;   // node id
    int lane = threadIdx.x & 63;
    if (wid >= N_NODES) return;
    int beg = offsets[wid], end = offsets[wid + 1];
    int grp = lane >> 4;        // 0..3
    int lig = lane & 15;        // lane in group

    // wsum sweep (csr is L2-hot)
    float wsum = 0.f;
    for (int c = beg; c < end; c += 64) {
        int j = c + lane;
        wsum += (j < end) ? hi16_of(csr[j]) : 0.f;
    }
    wsum = wave_sum(wsum);
    float inv = (end > beg) ? (1.0f / wsum) : 0.0f;

    float acc[8];
    #pragma unroll
    for (int k = 0; k < 8; ++k) acc[k] = 0.f;
    float msacc = 0.f;

    for (int c = beg; c < end; c += 64) {
        int j = c + lane;
        int cnt = end - c; if (cnt > 64) cnt = 64;
        unsigned u = (j < end) ? csr[j] : 0u;
        msacc += (j < end) ? __expf(-hi16_of(u) * inv) : 0.f;
        for (int it = 0; it < cnt; it += 8) {
            int idx1 = it + grp;
            int idx2 = it + 4 + grp;
            unsigned u1 = __shfl(u, idx1);
            unsigned u2 = __shfl(u, idx2);
            bool p1 = idx1 < cnt, p2 = idx2 < cnt;
            half8 v1, v2;
            float m1 = 0.f, m2 = 0.f;
            if (p1) {
                v1 = *(const half8*)(featH + (size_t)(u1 & 0xFFFFu) * F + lig * 8);
                m1 = __expf(-hi16_of(u1) * inv);
            }
            if (p2) {
                v2 = *(const half8*)(featH + (size_t)(u2 & 0xFFFFu) * F + lig * 8);
                m2 = __expf(-hi16_of(u2) * inv);
            }
            if (p1) {
                #pragma unroll
                for (int k = 0; k < 8; ++k) acc[k] += m1 * (float)v1[k];
            }
            if (p2) {
                #pragma unroll
                for (int k = 0; k < 8; ++k) acc[k] += m2 * (float)v2[k];
            }
        }
    }

    #pragma unroll
    for (int k = 0; k < 8; ++k) {
        acc[k] += __shfl_xor(acc[k], 16);
        acc[k] += __shfl_xor(acc[k], 32);
    }
    msacc = wave_sum(msacc);

    if (grp == 0) {
        half8 o;
        #pragma unroll
        for (int k = 0; k < 8; ++k) o[k] = (_Float16)acc[k];
        ((half8*)(aggH + (size_t)wid * F))[lig] = o;
    }
    if (lane == 0) msum[wid] = msacc;
}

// ---------------- fused_gemm: dual MFMA GEMM, weights staged in LDS ----------------
__global__ __launch_bounds__(512, 4) void fused_gemm(const _Float16* __restrict__ featH,
                                                     const _Float16* __restrict__ aggH,
                                                     const _Float16* __restrict__ WpH,
                                                     const float* __restrict__ bp,
                                                     const _Float16* __restrict__ WsH,
                                                     const float* __restrict__ bs,
                                                     const float* __restrict__ msum,
                                                     const int* __restrict__ offsets,
                                                     float* __restrict__ out) {
    __shared__ half8 sBS[2048];   // 32 KB
    __shared__ half8 sBP[2048];   // 32 KB

    int t = threadIdx.x;
    for (int c = t; c < 2048; c += 512) {
        int o  = c >> 4;
        int k8 = c & 15;
        int lane = (o & 15) | ((k8 & 3) << 4);
        int slot = ((o >> 4) * 4 + (k8 >> 2)) * 64 + lane;
        sBS[slot] = ((const half8*)WsH)[c];
        sBP[slot] = ((const half8*)WpH)[c];
    }
    __syncthreads();

    int wv   = t >> 6;
    int lane = t & 63;
    int n0   = blockIdx.x * 128 + wv * 16;   // tail waves compute garbage on pad rows; stores guarded
    int lrow = lane & 15;
    int quad = lane >> 4;

    floatx4 accS[8], accP[8];
    #pragma unroll
    for (int c = 0; c < 8; ++c) {
        accS[c] = (floatx4){0.f, 0.f, 0.f, 0.f};
        accP[c] = (floatx4){0.f, 0.f, 0.f, 0.f};
    }

    const half8* fr = (const half8*)(featH + (size_t)(n0 + lrow) * F) + quad;
    const half8* ar = (const half8*)(aggH  + (size_t)(n0 + lrow) * F) + quad;

    #pragma unroll
    for (int kt = 0; kt < 4; ++kt) {
        half8 aF = fr[kt * 4];
        half8 aA = ar[kt * 4];
        #pragma unroll
        for (int ct = 0; ct < 8; ++ct) {
            half8 bS = sBS[(ct * 4 + kt) * 64 + lane];
            half8 bP = sBP[(ct * 4 + kt) * 64 + lane];
            accS[ct] = __builtin_amdgcn_mfma_f32_16x16x32_f16(aF, bS, accS[ct], 0, 0, 0);
            accP[ct] = __builtin_amdgcn_mfma_f32_16x16x32_f16(aA, bP, accP[ct], 0, 0, 0);
        }
    }

    float ms[4], inv[4];
    int gn[4];
    #pragma unroll
    for (int r = 0; r < 4; ++r) {
        int g = n0 + quad * 4 + r;
        gn[r] = g;
        bool ok = g < N_NODES;
        ms[r]  = ok ? msum[g] : 0.f;
        float dv = ok ? fmaxf((float)(offsets[g + 1] - offsets[g]), 1.0f) : 1.0f;
        inv[r] = 1.0f / dv;
    }
    #pragma unroll
    for (int ct = 0; ct < 8; ++ct) {
        int c = ct * 16 + lrow;
        float bsv = bs[c], bpv = bp[c];
        #pragma unroll
        for (int r = 0; r < 4; ++r) {
            if (gn[r] < N_NODES)
                out[(size_t)gn[r] * F + c] = accS[ct][r] + bsv + (accP[ct][r] + ms[r] * bpv) * inv[r];
        }
    }
}

static inline char* align16(char* p) {
    return (char*)(((uintptr_t)p + 15) & ~(uintptr_t)15);
}

extern "C" void kernel_launch(void* const* d_in, const int* in_sizes, int n_in,
                              void* d_out, int out_size, void* d_ws, size_t ws_size,
                              hipStream_t stream) {
    const float* feat  = (const float*)d_in[0];
    const float* efeat = (const float*)d_in[1];
    const int*   src   = (const int*)d_in[2];
    const int*   dst   = (const int*)d_in[3];
    const float* Wp    = (const float*)d_in[4];
    const float* bp    = (const float*)d_in[5];
    const float* Ws    = (const float*)d_in[6];
    const float* bs    = (const float*)d_in[7];
    float* out = (float*)d_out;

    // workspace layout
    char* p = (char*)d_ws;
    int*      degR     = (int*)p;      p += (size_t)NREP * N_NODES * 4;     // zeroed
    int*      repBase  = (int*)p;      p += (size_t)NREP * N_NODES * 4;
    int*      deg      = (int*)p;      p += (size_t)N_NODES * 4;
    int*      offsets  = (int*)p;      p += (size_t)(N_NODES + 1) * 4;      p = align16(p);
    int*      blockSums= (int*)p;      p += (size_t)SCAN_BLK * 4;           p = align16(p);
    unsigned* csr      = (unsigned*)p; p += (size_t)N_EDGES * 4;            p = align16(p);
    float*    msum     = (float*)p;    p += (size_t)N_NODES * 4;            p = align16(p);
    _Float16* featH    = (_Float16*)p; p += (size_t)(N_NODES + PAD_ROWS) * F * 2; p = align16(p);
    _Float16* aggH     = (_Float16*)p; p += (size_t)(N_NODES + PAD_ROWS) * F * 2; p = align16(p);
    _Float16* WsH      = (_Float16*)p; p += (size_t)F * F * 2;              p = align16(p);
    _Float16* WpH      = (_Float16*)p;
    // rank lives in aggH's region: written by k_prep, read by k_fill,
    // both strictly before k_gather writes aggH. 3.2 MB <= 12.8 MB.
    int* rank = (int*)aggH;

    // zero degR (1.6 MB at ws base)
    hipMemsetAsync(d_ws, 0, (size_t)NREP * N_NODES * 4, stream);

    k_prep<<<(N_EDGES + 255) / 256, 256, 0, stream>>>(feat, Wp, Ws, dst, featH, WpH, WsH, degR, rank);
    k_scan1<<<SCAN_NB, SCAN_BLK, 0, stream>>>(degR, deg, repBase, blockSums);
    k_scan3<<<SCAN_NB, SCAN_BLK, 0, stream>>>(deg, blockSums, offsets);
    k_fill<<<(N_EDGES + 255) / 256, 256, 0, stream>>>(src, dst, efeat, offsets, repBase, rank, csr);
    k_gather<<<(N_NODES * 64 + 255) / 256, 256, 0, stream>>>(offsets, csr, featH, msum, aggH);
    fused_gemm<<<(N_NODES + 127) / 128, 512, 0, stream>>>(featH, aggH, WpH, bp, WsH, bs, msum, offsets, out);
}